// Round 10
// baseline (104.309 us; speedup 1.0000x reference)
//
#include <hip/hip_runtime.h>
#include <hip/hip_cooperative_groups.h>

namespace cg = cooperative_groups;

#define LEAKY 0.2f
#define B_TOT 8192
#define N_TOT 2048
#define D_TOT 128

// =================== single-launch cooperative kernel ===================
// 256 blocks x 256 threads. Phases: q-dots | rank | prefix tables | output.
__global__ __launch_bounds__(256) void gat_all(const float* __restrict__ patient,
                                               const float* __restrict__ disease,
                                               const float* __restrict__ ak,
                                               float* __restrict__ q,
                                               float* __restrict__ sortedq,
                                               float* __restrict__ eq1s,
                                               float* __restrict__ eq2s,
                                               int* __restrict__ perm,
                                               float* __restrict__ P1,
                                               float* __restrict__ P2,
                                               float* __restrict__ T1,
                                               float* __restrict__ T2,
                                               float* __restrict__ S1suf,
                                               float* __restrict__ S2pre,
                                               float* __restrict__ out) {
    cg::grid_group grid = cg::this_grid();

    __shared__ float sq[N_TOT];            // q (phase 2), sortedq (phase 4)
    __shared__ float suf1[33][128];
    __shared__ float pre2[33][128];
    __shared__ float a_s[D_TOT];
    __shared__ float p_s[32], e1_s[32], e2_s[32], inv_s[32];
    __shared__ int   c_s[32];
    __shared__ int   perm_s[64];
    __shared__ float e1l[64], e2l[64];
    __shared__ float seg1[2][128], seg2[2][128];
    __shared__ float wt1[4], wt2[4];

    const int tid  = threadIdx.x;
    const int b    = blockIdx.x;
    const int wave = tid >> 6;
    const int lane = tid & 63;

    // ---------- Phase 1: q[n] = disease[n,:] . a_n  (8 rows per block) ----------
    if (tid < D_TOT) a_s[tid] = ak[D_TOT + tid];
    __syncthreads();
    #pragma unroll
    for (int rr = 0; rr < 2; ++rr) {
        const int row = b * 8 + wave * 2 + rr;
        const float* src = disease + (size_t)row * D_TOT;
        float s = src[lane] * a_s[lane] + src[lane + 64] * a_s[lane + 64];
        #pragma unroll
        for (int off = 32; off; off >>= 1) s += __shfl_xor(s, off);
        if (lane == 0) q[row] = s;
    }
    grid.sync();

    // ---------- Phase 2: rank-by-count + scatter (8 elements per block) ----------
    for (int i = tid; i < N_TOT; i += 256) sq[i] = q[i];
    __syncthreads();
    {
        const int el  = tid >> 5;          // 0..7
        const int sub = tid & 31;
        const int k   = b * 8 + el;
        const float qk = sq[k];
        int cnt = 0;
        const int j0 = sub * 64;
        #pragma unroll 8
        for (int j = j0; j < j0 + 64; ++j) {
            const float qj = sq[j];
            cnt += (qj < qk || (qj == qk && j < k)) ? 1 : 0;
        }
        cnt += __shfl_xor(cnt, 1, 32);
        cnt += __shfl_xor(cnt, 2, 32);
        cnt += __shfl_xor(cnt, 4, 32);
        cnt += __shfl_xor(cnt, 8, 32);
        cnt += __shfl_xor(cnt, 16, 32);
        if (sub == 0) {
            sortedq[cnt] = qk;
            perm[cnt]    = k;
            eq1s[cnt]    = __expf(qk);
            eq2s[cnt]    = __expf(LEAKY * qk);
        }
    }
    grid.sync();

    // ---------- Phase 3: chunk prefix tables (blocks 0-31) + scalar scans (32) ----------
    if (b < 32) {
        if (tid < 64) {
            perm_s[tid] = perm[b * 64 + tid];
            e1l[tid] = eq1s[b * 64 + tid];
            e2l[tid] = eq2s[b * 64 + tid];
        }
        __syncthreads();
        const int col = tid & 127, seg = tid >> 7;   // 2 segs x 32 ranks
        const int r0 = b * 64;
        float d[32];
        #pragma unroll
        for (int jj = 0; jj < 32; ++jj)
            d[jj] = disease[(size_t)perm_s[seg * 32 + jj] * D_TOT + col];
        float s1 = 0.f, s2 = 0.f;
        #pragma unroll
        for (int jj = 0; jj < 32; ++jj) {
            s1 += e1l[seg * 32 + jj] * d[jj];
            s2 += e2l[seg * 32 + jj] * d[jj];
        }
        seg1[seg][col] = s1; seg2[seg][col] = s2;
        __syncthreads();
        float run1 = seg ? seg1[0][col] : 0.f;
        float run2 = seg ? seg2[0][col] : 0.f;
        #pragma unroll
        for (int jj = 0; jj < 32; ++jj) {
            const int j = seg * 32 + jj;
            P1[(size_t)(r0 + j) * D_TOT + col] = run1;
            P2[(size_t)(r0 + j) * D_TOT + col] = run2;
            run1 += e1l[j] * d[jj];
            run2 += e2l[j] * d[jj];
        }
        if (seg == 1) { T1[b * 128 + col] = run1; T2[b * 128 + col] = run2; }
    } else if (b == 32) {
        float a1[8], a2[8], s1[8], s2[8];
        #pragma unroll
        for (int i = 0; i < 8; ++i) { a1[i] = eq1s[tid * 8 + i]; a2[i] = eq2s[tid * 8 + i]; }
        float r1 = 0.f, r2 = 0.f;
        #pragma unroll
        for (int i = 0; i < 8; ++i) { r1 += a1[i]; s1[i] = r1; r2 += a2[i]; s2[i] = r2; }
        float i1 = r1, i2 = r2;
        #pragma unroll
        for (int off = 1; off < 64; off <<= 1) {
            const float v1 = __shfl_up(i1, off);
            const float v2 = __shfl_up(i2, off);
            if (lane >= off) { i1 += v1; i2 += v2; }
        }
        if (lane == 63) { wt1[wave] = i1; wt2[wave] = i2; }
        __syncthreads();
        float o1 = 0.f, o2 = 0.f, tt1 = 0.f, tt2 = 0.f;
        #pragma unroll
        for (int w = 0; w < 4; ++w) {
            tt1 += wt1[w]; tt2 += wt2[w];
            if (w < wave) { o1 += wt1[w]; o2 += wt2[w]; }
        }
        const float base1 = o1 + i1 - r1;   // exclusive prefix before elem tid*8
        const float base2 = o2 + i2 - r2;
        #pragma unroll
        for (int i = 0; i < 8; ++i) {
            const float EP1 = base1 + (i ? s1[i - 1] : 0.f);
            const float EP2 = base2 + (i ? s2[i - 1] : 0.f);
            S1suf[tid * 8 + i] = tt1 - EP1;   // sum over ranks >= idx
            S2pre[tid * 8 + i] = EP2;         // sum over ranks <  idx
        }
        if (tid == 0) { S1suf[N_TOT] = 0.f; S2pre[N_TOT] = tt2; }
    }
    grid.sync();

    // ---------- Phase 4: per-block 32-patient output ----------
    const int b0 = b * 32;
    for (int i = tid; i < N_TOT; i += 256) sq[i] = sortedq[i];
    if (tid < D_TOT) a_s[tid] = ak[tid];    // now a_p

    if (tid < 128) {                 // suf1[c] = sum_{c'>=c} T1  (batched loads)
        float t[32];
        #pragma unroll
        for (int cb = 0; cb < 32; ++cb) t[cb] = T1[cb * 128 + tid];
        float r = 0.f;
        suf1[32][tid] = 0.f;
        #pragma unroll
        for (int cb = 31; cb >= 0; --cb) { r += t[cb]; suf1[cb][tid] = r; }
    } else {
        const int col = tid - 128;
        float t[32];
        #pragma unroll
        for (int cb = 0; cb < 32; ++cb) t[cb] = T2[cb * 128 + col];
        float r = 0.f;
        #pragma unroll
        for (int cb = 0; cb < 32; ++cb) { pre2[cb][col] = r; r += t[cb]; }
        pre2[32][col] = r;
    }
    __syncthreads();

    // p-dots inline (patient rows stay cache-hot for the epilogue)
    #pragma unroll
    for (int rr = 0; rr < 8; ++rr) {
        const int row = wave * 8 + rr;
        const float* pr = patient + (size_t)(b0 + row) * D_TOT;
        float s = pr[lane] * a_s[lane] + pr[lane + 64] * a_s[lane + 64];
        #pragma unroll
        for (int off = 32; off; off >>= 1) s += __shfl_xor(s, off);
        if (lane == 0) p_s[row] = s;
    }
    __syncthreads();

    if (tid < 32) {
        const float pv = p_s[tid];
        const float qmax = sq[N_TOT - 1];
        const float xm = pv + qmax;
        const float m = fmaxf(xm, LEAKY * xm);      // row max (leaky monotonic)
        const float E1 = __expf(pv - m);
        const float E2 = __expf(LEAKY * pv - m);
        const float thr = -pv;
        int lo = 0, hi = N_TOT;
        while (lo < hi) {                           // first idx with sq[idx] > -pv
            const int mid = (lo + hi) >> 1;
            if (sq[mid] <= thr) lo = mid + 1; else hi = mid;
        }
        const float S = E1 * S1suf[lo] + E2 * S2pre[lo];
        e1_s[tid] = E1; e2_s[tid] = E2; inv_s[tid] = 1.0f / S; c_s[tid] = lo;
    }
    __syncthreads();

    const int row = tid >> 3;
    const int cb4 = (tid & 7) * 16;
    const int gr = b0 + row;
    const int c = c_s[row];
    const int bc = c >> 6;
    const float E1 = e1_s[row], E2 = e2_s[row], inv = inv_s[row];
    const bool has = (c < N_TOT);

    #pragma unroll
    for (int i = 0; i < 4; ++i) {
        const int col = cb4 + i * 4;
        float4 p1 = make_float4(0.f, 0.f, 0.f, 0.f);
        float4 p2 = make_float4(0.f, 0.f, 0.f, 0.f);
        if (has) {
            p1 = *(const float4*)&P1[(size_t)c * D_TOT + col];
            p2 = *(const float4*)&P2[(size_t)c * D_TOT + col];
        }
        const float4 pat = *(const float4*)&patient[(size_t)gr * D_TOT + col];
        float4 o;
        o.x = pat.x + (E1 * (suf1[bc][col + 0] - p1.x) + E2 * (pre2[bc][col + 0] + p2.x)) * inv;
        o.y = pat.y + (E1 * (suf1[bc][col + 1] - p1.y) + E2 * (pre2[bc][col + 1] + p2.y)) * inv;
        o.z = pat.z + (E1 * (suf1[bc][col + 2] - p1.z) + E2 * (pre2[bc][col + 2] + p2.z)) * inv;
        o.w = pat.w + (E1 * (suf1[bc][col + 3] - p1.w) + E2 * (pre2[bc][col + 3] + p2.w)) * inv;
        *(float4*)&out[(size_t)gr * D_TOT + col] = o;
    }
}

// =================== 4-launch fallback (round-9, known-passing) ===================
__global__ __launch_bounds__(256) void q_kernel(const float* __restrict__ disease,
                                                const float* __restrict__ ak,
                                                float* __restrict__ q) {
    const int gid  = blockIdx.x * 256 + threadIdx.x;
    const int wid  = gid >> 6;
    const int lane = gid & 63;
    const float* src = disease + (size_t)wid * D_TOT;
    float s = src[lane] * ak[D_TOT + lane] + src[lane + 64] * ak[D_TOT + lane + 64];
    #pragma unroll
    for (int off = 32; off; off >>= 1) s += __shfl_xor(s, off);
    if (lane == 0) q[wid] = s;
}

__global__ __launch_bounds__(256) void rank_kernel(const float* __restrict__ q,
                                                   float* __restrict__ sortedq,
                                                   float* __restrict__ eq1s,
                                                   float* __restrict__ eq2s,
                                                   int* __restrict__ perm) {
    __shared__ float q_s[N_TOT];
    const int tid = threadIdx.x;
    for (int i = tid; i < N_TOT; i += 256) q_s[i] = q[i];
    __syncthreads();
    const int kl = tid >> 3, sub = tid & 7;
    const int k = blockIdx.x * 32 + kl;
    const float qk = q_s[k];
    int cnt = 0;
    const int j0 = sub * 256;
    #pragma unroll 8
    for (int j = j0; j < j0 + 256; ++j) {
        float qj = q_s[j];
        cnt += (qj < qk || (qj == qk && j < k)) ? 1 : 0;
    }
    cnt += __shfl_xor(cnt, 1);
    cnt += __shfl_xor(cnt, 2);
    cnt += __shfl_xor(cnt, 4);
    if (sub == 0) {
        sortedq[cnt] = qk;
        perm[cnt]    = k;
        eq1s[cnt]    = __expf(qk);
        eq2s[cnt]    = __expf(LEAKY * qk);
    }
}

__global__ __launch_bounds__(512) void scan_kernel(const float* __restrict__ disease,
                                                   const float* __restrict__ eq1s,
                                                   const float* __restrict__ eq2s,
                                                   const int* __restrict__ perm,
                                                   float* __restrict__ P1,
                                                   float* __restrict__ P2,
                                                   float* __restrict__ T1,
                                                   float* __restrict__ T2,
                                                   float* __restrict__ S1suf,
                                                   float* __restrict__ S2pre) {
    const int tid = threadIdx.x;
    const int b = blockIdx.x;
    if (b < 32) {
        __shared__ int   perm_s[64];
        __shared__ float e1l[64], e2l[64];
        __shared__ float seg1[4][128], seg2[4][128];
        const int r0 = b * 64;
        if (tid < 64) {
            perm_s[tid] = perm[r0 + tid];
            e1l[tid] = eq1s[r0 + tid];
            e2l[tid] = eq2s[r0 + tid];
        }
        __syncthreads();
        const int col = tid & 127, seg = tid >> 7;
        float d[16];
        #pragma unroll
        for (int jj = 0; jj < 16; ++jj)
            d[jj] = disease[(size_t)perm_s[seg * 16 + jj] * D_TOT + col];
        float s1 = 0.f, s2 = 0.f;
        #pragma unroll
        for (int jj = 0; jj < 16; ++jj) {
            s1 += e1l[seg * 16 + jj] * d[jj];
            s2 += e2l[seg * 16 + jj] * d[jj];
        }
        seg1[seg][col] = s1; seg2[seg][col] = s2;
        __syncthreads();
        float run1 = 0.f, run2 = 0.f;
        for (int s = 0; s < seg; ++s) { run1 += seg1[s][col]; run2 += seg2[s][col]; }
        #pragma unroll
        for (int jj = 0; jj < 16; ++jj) {
            const int j = seg * 16 + jj;
            P1[(size_t)(r0 + j) * D_TOT + col] = run1;
            P2[(size_t)(r0 + j) * D_TOT + col] = run2;
            run1 += e1l[j] * d[jj];
            run2 += e2l[j] * d[jj];
        }
        if (seg == 3) { T1[b * 128 + col] = run1; T2[b * 128 + col] = run2; }
    } else {
        __shared__ float w1[8], w2[8];
        const int lane = tid & 63, wv = tid >> 6;
        float a1[4], a2[4], s1[4], s2[4];
        #pragma unroll
        for (int i = 0; i < 4; ++i) { a1[i] = eq1s[tid * 4 + i]; a2[i] = eq2s[tid * 4 + i]; }
        float r1 = 0.f, r2 = 0.f;
        #pragma unroll
        for (int i = 0; i < 4; ++i) { r1 += a1[i]; s1[i] = r1; r2 += a2[i]; s2[i] = r2; }
        float i1 = r1, i2 = r2;
        #pragma unroll
        for (int off = 1; off < 64; off <<= 1) {
            float v1 = __shfl_up(i1, off);
            float v2 = __shfl_up(i2, off);
            if (lane >= off) { i1 += v1; i2 += v2; }
        }
        if (lane == 63) { w1[wv] = i1; w2[wv] = i2; }
        __syncthreads();
        float o1 = 0.f, o2 = 0.f, tot1 = 0.f, tot2 = 0.f;
        #pragma unroll
        for (int w = 0; w < 8; ++w) {
            tot1 += w1[w]; tot2 += w2[w];
            if (w < wv) { o1 += w1[w]; o2 += w2[w]; }
        }
        const float base1 = o1 + i1 - r1;
        const float base2 = o2 + i2 - r2;
        #pragma unroll
        for (int i = 0; i < 4; ++i) {
            const float EP1 = base1 + (i ? s1[i - 1] : 0.f);
            const float EP2 = base2 + (i ? s2[i - 1] : 0.f);
            S1suf[tid * 4 + i] = tot1 - EP1;
            S2pre[tid * 4 + i] = EP2;
        }
        if (tid == 0) { S1suf[N_TOT] = 0.f; S2pre[N_TOT] = tot2; }
    }
}

__global__ __launch_bounds__(256) void gat_ps(const float* __restrict__ patient,
                                              const float* __restrict__ ak,
                                              const float* __restrict__ sortedq,
                                              const float* __restrict__ P1,
                                              const float* __restrict__ P2,
                                              const float* __restrict__ T1,
                                              const float* __restrict__ T2,
                                              const float* __restrict__ S1suf,
                                              const float* __restrict__ S2pre,
                                              float* __restrict__ out) {
    __shared__ float sq[N_TOT];
    __shared__ float suf1[33][128];
    __shared__ float pre2[33][128];
    __shared__ float a_s[D_TOT];
    __shared__ float p_s[32];
    __shared__ float e1_s[32], e2_s[32], inv_s[32];
    __shared__ int   c_s[32];
    const int tid = threadIdx.x;
    const int b0 = blockIdx.x * 32;

    for (int i = tid; i < N_TOT; i += 256) sq[i] = sortedq[i];
    if (tid < D_TOT) a_s[tid] = ak[tid];

    if (tid < 128) {
        float t[32];
        #pragma unroll
        for (int b = 0; b < 32; ++b) t[b] = T1[b * 128 + tid];
        float r = 0.f;
        suf1[32][tid] = 0.f;
        #pragma unroll
        for (int b = 31; b >= 0; --b) { r += t[b]; suf1[b][tid] = r; }
    } else {
        const int col = tid - 128;
        float t[32];
        #pragma unroll
        for (int b = 0; b < 32; ++b) t[b] = T2[b * 128 + col];
        float r = 0.f;
        #pragma unroll
        for (int b = 0; b < 32; ++b) { pre2[b][col] = r; r += t[b]; }
        pre2[32][col] = r;
    }
    __syncthreads();

    const int wave = tid >> 6, lane = tid & 63;
    #pragma unroll
    for (int rr = 0; rr < 8; ++rr) {
        const int row = wave * 8 + rr;
        const float* pr = patient + (size_t)(b0 + row) * D_TOT;
        float s = pr[lane] * a_s[lane] + pr[lane + 64] * a_s[lane + 64];
        #pragma unroll
        for (int off = 32; off; off >>= 1) s += __shfl_xor(s, off);
        if (lane == 0) p_s[row] = s;
    }
    __syncthreads();

    if (tid < 32) {
        const float pv = p_s[tid];
        const float qmax = sq[N_TOT - 1];
        const float xm = pv + qmax;
        const float m = fmaxf(xm, LEAKY * xm);
        const float E1 = __expf(pv - m);
        const float E2 = __expf(LEAKY * pv - m);
        const float thr = -pv;
        int lo = 0, hi = N_TOT;
        while (lo < hi) {
            int mid = (lo + hi) >> 1;
            if (sq[mid] <= thr) lo = mid + 1; else hi = mid;
        }
        const float S = E1 * S1suf[lo] + E2 * S2pre[lo];
        e1_s[tid] = E1; e2_s[tid] = E2; inv_s[tid] = 1.0f / S; c_s[tid] = lo;
    }
    __syncthreads();

    const int row = tid >> 3;
    const int cb = (tid & 7) * 16;
    const int gr = b0 + row;
    const int c = c_s[row];
    const int bc = c >> 6;
    const float E1 = e1_s[row], E2 = e2_s[row], inv = inv_s[row];
    const bool has = (c < N_TOT);

    #pragma unroll
    for (int i = 0; i < 4; ++i) {
        const int col = cb + i * 4;
        float4 p1 = make_float4(0.f, 0.f, 0.f, 0.f);
        float4 p2 = make_float4(0.f, 0.f, 0.f, 0.f);
        if (has) {
            p1 = *(const float4*)&P1[(size_t)c * D_TOT + col];
            p2 = *(const float4*)&P2[(size_t)c * D_TOT + col];
        }
        const float4 pat = *(const float4*)&patient[(size_t)gr * D_TOT + col];
        float4 o;
        o.x = pat.x + (E1 * (suf1[bc][col + 0] - p1.x) + E2 * (pre2[bc][col + 0] + p2.x)) * inv;
        o.y = pat.y + (E1 * (suf1[bc][col + 1] - p1.y) + E2 * (pre2[bc][col + 1] + p2.y)) * inv;
        o.z = pat.z + (E1 * (suf1[bc][col + 2] - p1.z) + E2 * (pre2[bc][col + 2] + p2.z)) * inv;
        o.w = pat.w + (E1 * (suf1[bc][col + 3] - p1.w) + E2 * (pre2[bc][col + 3] + p2.w)) * inv;
        *(float4*)&out[(size_t)gr * D_TOT + col] = o;
    }
}

// =================== tiny fallback (round-1, known-passing) ===================
__global__ __launch_bounds__(256) void pq_fb(const float* __restrict__ patient,
                                             const float* __restrict__ disease,
                                             const float* __restrict__ ak,
                                             float* __restrict__ p,
                                             float* __restrict__ q) {
    int gid  = blockIdx.x * blockDim.x + threadIdx.x;
    int wid  = gid >> 6;
    int lane = gid & 63;
    const float* src;
    const float* a;
    float* dst;
    if (wid < B_TOT) {
        src = patient + (size_t)wid * D_TOT; a = ak; dst = p + wid;
    } else {
        src = disease + (size_t)(wid - B_TOT) * D_TOT; a = ak + D_TOT; dst = q + (wid - B_TOT);
    }
    float s = src[lane] * a[lane] + src[lane + 64] * a[lane + 64];
    #pragma unroll
    for (int off = 32; off; off >>= 1) s += __shfl_xor(s, off);
    if (lane == 0) *dst = s;
}

#define FBP 16
#define FNT 256
__global__ __launch_bounds__(256) void gat_fb(const float* __restrict__ patient,
                                              const float* __restrict__ disease,
                                              const float* __restrict__ p,
                                              const float* __restrict__ q,
                                              float* __restrict__ out) {
    __shared__ float q_s[N_TOT];
    __shared__ float w_s[FBP][FNT];
    __shared__ float m_s[FBP], S_s[FBP], pp_s[FBP];
    const int tid = threadIdx.x;
    const int b0  = blockIdx.x * FBP;
    for (int i = tid; i < N_TOT; i += 256) q_s[i] = q[i];
    if (tid < FBP) pp_s[tid] = p[b0 + tid];
    __syncthreads();
    const int wave = tid >> 6, lane = tid & 63;
    for (int pi = wave * 4; pi < wave * 4 + 4; ++pi) {
        float pp = pp_s[pi];
        float mx = -1e30f;
        for (int n = lane; n < N_TOT; n += 64) {
            float x = pp + q_s[n]; x = x > 0.0f ? x : LEAKY * x; mx = fmaxf(mx, x);
        }
        #pragma unroll
        for (int off = 32; off; off >>= 1) mx = fmaxf(mx, __shfl_xor(mx, off));
        float sum = 0.0f;
        for (int n = lane; n < N_TOT; n += 64) {
            float x = pp + q_s[n]; x = x > 0.0f ? x : LEAKY * x; sum += __expf(x - mx);
        }
        #pragma unroll
        for (int off = 32; off; off >>= 1) sum += __shfl_xor(sum, off);
        if (lane == 0) { m_s[pi] = mx; S_s[pi] = sum; }
    }
    __syncthreads();
    const int d2 = tid & 31;
    const int pg = tid >> 5;
    const int p0 = 2 * pg, p1 = 2 * pg + 1;
    float4 acc0 = make_float4(0.f, 0.f, 0.f, 0.f);
    float4 acc1 = make_float4(0.f, 0.f, 0.f, 0.f);
    for (int n0 = 0; n0 < N_TOT; n0 += FNT) {
        __syncthreads();
        for (int i = tid; i < FBP * FNT; i += 256) {
            int pi = i >> 8;
            int nt = i & (FNT - 1);
            float x = pp_s[pi] + q_s[n0 + nt];
            x = x > 0.0f ? x : LEAKY * x;
            w_s[pi][nt] = __expf(x - m_s[pi]);
        }
        __syncthreads();
        const float* drow = disease + (size_t)n0 * D_TOT + d2 * 4;
        #pragma unroll 4
        for (int nt = 0; nt < FNT; ++nt) {
            float4 dv = *reinterpret_cast<const float4*>(drow + (size_t)nt * D_TOT);
            float w0 = w_s[p0][nt];
            float w1 = w_s[p1][nt];
            acc0.x += w0 * dv.x; acc0.y += w0 * dv.y; acc0.z += w0 * dv.z; acc0.w += w0 * dv.w;
            acc1.x += w1 * dv.x; acc1.y += w1 * dv.y; acc1.z += w1 * dv.z; acc1.w += w1 * dv.w;
        }
    }
    const float inv0 = 1.0f / S_s[p0];
    const float inv1 = 1.0f / S_s[p1];
    {
        size_t off = (size_t)(b0 + p0) * D_TOT + d2 * 4;
        float4 pf = *reinterpret_cast<const float4*>(patient + off);
        float4 o;
        o.x = pf.x + acc0.x * inv0; o.y = pf.y + acc0.y * inv0;
        o.z = pf.z + acc0.z * inv0; o.w = pf.w + acc0.w * inv0;
        *reinterpret_cast<float4*>(reinterpret_cast<float*>(out) + off) = o;
    }
    {
        size_t off = (size_t)(b0 + p1) * D_TOT + d2 * 4;
        float4 pf = *reinterpret_cast<const float4*>(patient + off);
        float4 o;
        o.x = pf.x + acc1.x * inv1; o.y = pf.y + acc1.y * inv1;
        o.z = pf.z + acc1.z * inv1; o.w = pf.w + acc1.w * inv1;
        *reinterpret_cast<float4*>(reinterpret_cast<float*>(out) + off) = o;
    }
}

extern "C" void kernel_launch(void* const* d_in, const int* in_sizes, int n_in,
                              void* d_out, int out_size, void* d_ws, size_t ws_size,
                              hipStream_t stream) {
    const float* patient = (const float*)d_in[0];   // 8192 x 128
    const float* disease = (const float*)d_in[1];   // 2048 x 128
    const float* ak      = (const float*)d_in[2];   // 256
    float* out = (float*)d_out;
    char* w = (char*)d_ws;

    const size_t oP1 = 0;                  // [2048][128] f32 = 1 MB
    const size_t oP2 = 1048576;            // 1 MB
    const size_t oT1 = 2097152;            // 16 KB
    const size_t oT2 = 2113536;            // 16 KB
    const size_t oS1 = 2129920;            // [2049]
    const size_t oS2 = 2138368;
    const size_t oSQ = 2146816;            // sortedq
    const size_t oE1 = 2155008;
    const size_t oE2 = 2163200;
    const size_t oPM = 2171392;            // perm
    const size_t oQ  = 2179584;            // q
    const size_t need_fast = 2220544;

    if (ws_size >= need_fast) {
        float* P1 = (float*)(w + oP1);
        float* P2 = (float*)(w + oP2);
        float* T1 = (float*)(w + oT1);
        float* T2 = (float*)(w + oT2);
        float* S1 = (float*)(w + oS1);
        float* S2 = (float*)(w + oS2);
        float* sq = (float*)(w + oSQ);
        float* e1 = (float*)(w + oE1);
        float* e2 = (float*)(w + oE2);
        int*   pm = (int*)  (w + oPM);
        float* q  = (float*)(w + oQ);

        void* args[] = {(void*)&patient, (void*)&disease, (void*)&ak,
                        (void*)&q, (void*)&sq, (void*)&e1, (void*)&e2, (void*)&pm,
                        (void*)&P1, (void*)&P2, (void*)&T1, (void*)&T2,
                        (void*)&S1, (void*)&S2, (void*)&out};
        hipError_t err = hipLaunchCooperativeKernel((void*)gat_all, dim3(256), dim3(256),
                                                    args, 0, stream);
        if (err != hipSuccess) {
            // 4-launch fallback (same buffers, deterministic)
            q_kernel<<<N_TOT / 4, 256, 0, stream>>>(disease, ak, q);
            rank_kernel<<<N_TOT / 32, 256, 0, stream>>>(q, sq, e1, e2, pm);
            scan_kernel<<<33, 512, 0, stream>>>(disease, e1, e2, pm, P1, P2, T1, T2, S1, S2);
            gat_ps<<<B_TOT / 32, 256, 0, stream>>>(patient, ak, sq, P1, P2, T1, T2, S1, S2, out);
        }
    } else {
        float* p = (float*)d_ws;
        float* q = p + B_TOT;
        pq_fb<<<(B_TOT + N_TOT) / 4, 256, 0, stream>>>(patient, disease, ak, p, q);
        gat_fb<<<B_TOT / FBP, 256, 0, stream>>>(patient, disease, p, q, out);
    }
}

// Round 11
// 26.546 us; speedup vs baseline: 3.9294x; 3.9294x over previous
//
#include <hip/hip_runtime.h>
#include <hip/hip_bf16.h>

#define LEAKY 0.2f
#define B_TOT 8192
#define N_TOT 2048
#define D_TOT 128
#define BM 16

typedef float f32x4 __attribute__((ext_vector_type(4)));
typedef short bf16x8 __attribute__((ext_vector_type(8)));
typedef unsigned short u16x8 __attribute__((ext_vector_type(8)));

static __device__ __forceinline__ unsigned short f2bf(float x) {
    return __builtin_bit_cast(unsigned short, __float2bfloat16(x));
}

// ---------------- prep: q-dots + fragment-ordered bf16 DnT ----------------
__global__ __launch_bounds__(256) void prep_kernel(const float* __restrict__ disease,
                                                   const float* __restrict__ ak,
                                                   float* __restrict__ q,
                                                   uint4* __restrict__ DnTf) {
    __shared__ float tile[32][129];   // +1 pad
    __shared__ float a_s[D_TOT];
    const int tid = threadIdx.x;
    const int b = blockIdx.x;
    const int r0 = b * 32;

    if (tid < D_TOT) a_s[tid] = ak[D_TOT + tid];
    #pragma unroll
    for (int t = 0; t < 4; ++t) {
        int idx = tid + t * 256;          // 0..1023 float4 slots
        int row = idx >> 5;
        int cv = (idx & 31) * 4;
        float4 v = *(const float4*)(disease + (size_t)(r0 + row) * D_TOT + cv);
        tile[row][cv] = v.x; tile[row][cv + 1] = v.y;
        tile[row][cv + 2] = v.z; tile[row][cv + 3] = v.w;
    }
    __syncthreads();

    const int wave = tid >> 6, lane = tid & 63;
    #pragma unroll
    for (int rr = 0; rr < 8; ++rr) {
        int r = wave * 8 + rr;
        float s = tile[r][lane] * a_s[lane] + tile[r][lane + 64] * a_s[lane + 64];
        #pragma unroll
        for (int off = 32; off; off >>= 1) s += __shfl_xor(s, off);
        if (lane == 0) q[r0 + r] = s;
    }

    #pragma unroll
    for (int h = 0; h < 2; ++h) {
        const int c  = tid + h * 256;     // 0..511
        const int kg = c >> 7;            // 0..3
        const int col = c & 127;
        const int ct = col >> 4, cl = col & 15;
        unsigned u[4];
        #pragma unroll
        for (int jj = 0; jj < 4; ++jj) {
            unsigned lo = f2bf(tile[kg * 8 + 2 * jj][col]);
            unsigned hi = f2bf(tile[kg * 8 + 2 * jj + 1][col]);
            u[jj] = lo | (hi << 16);
        }
        DnTf[((size_t)b * 8 + ct) * 64 + kg * 16 + cl] = make_uint4(u[0], u[1], u[2], u[3]);
    }
}

// ---------------- main: register-lean, true 8 waves/SIMD ----------------
// 512 blocks x 1024 threads, 2 blocks/CU. 16 waves = cw(2) x kq(8).
__global__ __launch_bounds__(1024, 8) void gat_mfma(const float* __restrict__ patient,
                                                    const float* __restrict__ ak,
                                                    const float* __restrict__ q,
                                                    const uint4* __restrict__ DnTf,
                                                    float* __restrict__ out) {
    __shared__ __align__(16) float eq1_s[N_TOT];
    __shared__ __align__(16) float eq2_s[N_TOT];
    __shared__ float red_s[7][2][1024];   // [kq-1][cw][t*256+(kg*4+i)*16+cl]
    __shared__ float a_s[D_TOT];
    __shared__ float p_s[BM], E1_s[BM], E2_s[BM], S_s[BM];
    __shared__ float red16[16];

    const int tid  = threadIdx.x;
    const int wave = tid >> 6;
    const int lane = tid & 63;
    const int b0   = blockIdx.x * BM;

    if (tid < D_TOT) a_s[tid] = ak[tid];
    __syncthreads();

    // eq1/eq2 + qmax partials
    float mx = -1e30f;
    for (int i = tid; i < N_TOT; i += 1024) {
        float qq = q[i];
        eq1_s[i] = __expf(qq);
        eq2_s[i] = __expf(LEAKY * qq);
        mx = fmaxf(mx, qq);
    }
    #pragma unroll
    for (int off = 32; off; off >>= 1) mx = fmaxf(mx, __shfl_xor(mx, off));
    if (lane == 0) red16[wave] = mx;

    // p-dot: wave w handles row w
    {
        const float* pr = patient + (size_t)(b0 + wave) * D_TOT;
        float s = pr[lane] * a_s[lane] + pr[lane + 64] * a_s[lane + 64];
        #pragma unroll
        for (int off = 32; off; off >>= 1) s += __shfl_xor(s, off);
        if (lane == 0) p_s[wave] = s;
    }
    __syncthreads();

    if (tid < BM) {
        float qmax = red16[0];
        #pragma unroll
        for (int i = 1; i < 16; ++i) qmax = fmaxf(qmax, red16[i]);
        const float pv = p_s[tid];
        const float xm = pv + qmax;
        const float m = fmaxf(xm, LEAKY * xm);    // row max (leaky monotonic)
        E1_s[tid] = __expf(pv - m);
        E2_s[tid] = __expf(LEAKY * pv - m);
    }
    __syncthreads();

    // S per row (wave w -> row w): S = sum_n max(E1*eq1, E2*eq2)  (exact)
    {
        const float E1 = E1_s[wave], E2 = E2_s[wave];
        float s = 0.f;
        for (int n = lane; n < N_TOT; n += 64)
            s += fmaxf(E1 * eq1_s[n], E2 * eq2_s[n]);
        #pragma unroll
        for (int off = 32; off; off >>= 1) s += __shfl_xor(s, off);
        if (lane == 0) S_s[wave] = s;
    }
    __syncthreads();

    // ---- barrier-free MFMA K-loop (register-lean) ----
    const int cl = lane & 15;
    const int kg = lane >> 4;
    const int cw = wave & 1;          // 64-col half
    const int kq = wave >> 1;         // K eighth (0..7)

    const float E1A = E1_s[cl], E2A = E2_s[cl];
    const uint4* fbase = DnTf + (size_t)(cw * 4) * 64 + lane;   // + kt*512 + t*64

    f32x4 acc[4] = {};

    for (int kt = kq * 8; kt < kq * 8 + 8; ++kt) {
        const uint4* fp = fbase + (size_t)kt * 512;
        const uint4 b0v = fp[0];
        const uint4 b1v = fp[64];
        const uint4 b2v = fp[128];
        const uint4 b3v = fp[192];

        const int gk = kt * 32 + kg * 8;
        u16x8 aw;
        {
            const float4 e1 = *(const float4*)&eq1_s[gk];
            const float4 e2 = *(const float4*)&eq2_s[gk];
            aw[0] = f2bf(fmaxf(E1A * e1.x, E2A * e2.x));
            aw[1] = f2bf(fmaxf(E1A * e1.y, E2A * e2.y));
            aw[2] = f2bf(fmaxf(E1A * e1.z, E2A * e2.z));
            aw[3] = f2bf(fmaxf(E1A * e1.w, E2A * e2.w));
        }
        {
            const float4 e1 = *(const float4*)&eq1_s[gk + 4];
            const float4 e2 = *(const float4*)&eq2_s[gk + 4];
            aw[4] = f2bf(fmaxf(E1A * e1.x, E2A * e2.x));
            aw[5] = f2bf(fmaxf(E1A * e1.y, E2A * e2.y));
            aw[6] = f2bf(fmaxf(E1A * e1.z, E2A * e2.z));
            aw[7] = f2bf(fmaxf(E1A * e1.w, E2A * e2.w));
        }
        const bf16x8 a0 = __builtin_bit_cast(bf16x8, aw);

        acc[0] = __builtin_amdgcn_mfma_f32_16x16x32_bf16(a0, __builtin_bit_cast(bf16x8, b0v), acc[0], 0, 0, 0);
        acc[1] = __builtin_amdgcn_mfma_f32_16x16x32_bf16(a0, __builtin_bit_cast(bf16x8, b1v), acc[1], 0, 0, 0);
        acc[2] = __builtin_amdgcn_mfma_f32_16x16x32_bf16(a0, __builtin_bit_cast(bf16x8, b2v), acc[2], 0, 0, 0);
        acc[3] = __builtin_amdgcn_mfma_f32_16x16x32_bf16(a0, __builtin_bit_cast(bf16x8, b3v), acc[3], 0, 0, 0);
    }

    // ---- split-K reduction ----
    __syncthreads();
    if (kq > 0) {
        float* rb = &red_s[kq - 1][cw][0];
        #pragma unroll
        for (int t = 0; t < 4; ++t)
            #pragma unroll
            for (int i = 0; i < 4; ++i)
                rb[t * 256 + (kg * 4 + i) * 16 + cl] = acc[t][i];
    }
    __syncthreads();
    if (kq == 0) {
        #pragma unroll
        for (int t = 0; t < 4; ++t)
            #pragma unroll
            for (int i = 0; i < 4; ++i) {
                const int idx = t * 256 + (kg * 4 + i) * 16 + cl;
                float s = acc[t][i];
                #pragma unroll
                for (int j = 0; j < 7; ++j) s += red_s[j][cw][idx];
                acc[t][i] = s;
            }
        float inv[4];
        #pragma unroll
        for (int i = 0; i < 4; ++i) inv[i] = 1.0f / S_s[kg * 4 + i];
        #pragma unroll
        for (int t = 0; t < 4; ++t)
            #pragma unroll
            for (int i = 0; i < 4; ++i) {
                const int row = b0 + kg * 4 + i;
                const int col = cw * 64 + t * 16 + cl;
                out[(size_t)row * D_TOT + col] =
                    patient[(size_t)row * D_TOT + col] + acc[t][i] * inv[i];
            }
    }
}

// ---------------- fallback path (round-1, known-passing) ----------------
__global__ __launch_bounds__(256) void pq_fb(const float* __restrict__ patient,
                                             const float* __restrict__ disease,
                                             const float* __restrict__ ak,
                                             float* __restrict__ p,
                                             float* __restrict__ q) {
    int gid  = blockIdx.x * blockDim.x + threadIdx.x;
    int wid  = gid >> 6;
    int lane = gid & 63;
    const float* src;
    const float* a;
    float* dst;
    if (wid < B_TOT) {
        src = patient + (size_t)wid * D_TOT; a = ak; dst = p + wid;
    } else {
        src = disease + (size_t)(wid - B_TOT) * D_TOT; a = ak + D_TOT; dst = q + (wid - B_TOT);
    }
    float s = src[lane] * a[lane] + src[lane + 64] * a[lane + 64];
    #pragma unroll
    for (int off = 32; off; off >>= 1) s += __shfl_xor(s, off);
    if (lane == 0) *dst = s;
}

#define FBP 16
#define FNT 256
__global__ __launch_bounds__(256) void gat_fb(const float* __restrict__ patient,
                                              const float* __restrict__ disease,
                                              const float* __restrict__ p,
                                              const float* __restrict__ q,
                                              float* __restrict__ out) {
    __shared__ float q_s[N_TOT];
    __shared__ float w_s[FBP][FNT];
    __shared__ float m_s[FBP], S_s[FBP], pp_s[FBP];
    const int tid = threadIdx.x;
    const int b0  = blockIdx.x * FBP;
    for (int i = tid; i < N_TOT; i += 256) q_s[i] = q[i];
    if (tid < FBP) pp_s[tid] = p[b0 + tid];
    __syncthreads();
    const int wave = tid >> 6, lane = tid & 63;
    for (int pi = wave * 4; pi < wave * 4 + 4; ++pi) {
        float pp = pp_s[pi];
        float mx = -1e30f;
        for (int n = lane; n < N_TOT; n += 64) {
            float x = pp + q_s[n]; x = x > 0.0f ? x : LEAKY * x; mx = fmaxf(mx, x);
        }
        #pragma unroll
        for (int off = 32; off; off >>= 1) mx = fmaxf(mx, __shfl_xor(mx, off));
        float sum = 0.0f;
        for (int n = lane; n < N_TOT; n += 64) {
            float x = pp + q_s[n]; x = x > 0.0f ? x : LEAKY * x; sum += __expf(x - mx);
        }
        #pragma unroll
        for (int off = 32; off; off >>= 1) sum += __shfl_xor(sum, off);
        if (lane == 0) { m_s[pi] = mx; S_s[pi] = sum; }
    }
    __syncthreads();
    const int d2 = tid & 31;
    const int pg = tid >> 5;
    const int p0 = 2 * pg, p1 = 2 * pg + 1;
    float4 acc0 = make_float4(0.f, 0.f, 0.f, 0.f);
    float4 acc1 = make_float4(0.f, 0.f, 0.f, 0.f);
    for (int n0 = 0; n0 < N_TOT; n0 += FNT) {
        __syncthreads();
        for (int i = tid; i < FBP * FNT; i += 256) {
            int pi = i >> 8;
            int nt = i & (FNT - 1);
            float x = pp_s[pi] + q_s[n0 + nt];
            x = x > 0.0f ? x : LEAKY * x;
            w_s[pi][nt] = __expf(x - m_s[pi]);
        }
        __syncthreads();
        const float* drow = disease + (size_t)n0 * D_TOT + d2 * 4;
        #pragma unroll 4
        for (int nt = 0; nt < FNT; ++nt) {
            float4 dv = *reinterpret_cast<const float4*>(drow + (size_t)nt * D_TOT);
            float w0 = w_s[p0][nt];
            float w1 = w_s[p1][nt];
            acc0.x += w0 * dv.x; acc0.y += w0 * dv.y; acc0.z += w0 * dv.z; acc0.w += w0 * dv.w;
            acc1.x += w1 * dv.x; acc1.y += w1 * dv.y; acc1.z += w1 * dv.z; acc1.w += w1 * dv.w;
        }
    }
    const float inv0 = 1.0f / S_s[p0];
    const float inv1 = 1.0f / S_s[p1];
    {
        size_t off = (size_t)(b0 + p0) * D_TOT + d2 * 4;
        float4 pf = *reinterpret_cast<const float4*>(patient + off);
        float4 o;
        o.x = pf.x + acc0.x * inv0; o.y = pf.y + acc0.y * inv0;
        o.z = pf.z + acc0.z * inv0; o.w = pf.w + acc0.w * inv0;
        *reinterpret_cast<float4*>(reinterpret_cast<float*>(out) + off) = o;
    }
    {
        size_t off = (size_t)(b0 + p1) * D_TOT + d2 * 4;
        float4 pf = *reinterpret_cast<const float4*>(patient + off);
        float4 o;
        o.x = pf.x + acc1.x * inv1; o.y = pf.y + acc1.y * inv1;
        o.z = pf.z + acc1.z * inv1; o.w = pf.w + acc1.w * inv1;
        *reinterpret_cast<float4*>(reinterpret_cast<float*>(out) + off) = o;
    }
}

extern "C" void kernel_launch(void* const* d_in, const int* in_sizes, int n_in,
                              void* d_out, int out_size, void* d_ws, size_t ws_size,
                              hipStream_t stream) {
    const float* patient = (const float*)d_in[0];   // 8192 x 128
    const float* disease = (const float*)d_in[1];   // 2048 x 128
    const float* ak      = (const float*)d_in[2];   // 256
    float* out = (float*)d_out;

    const size_t need_fast = (size_t)512 * 1024 + 8192;   // DnTf (512KB) + q (8KB)
    if (ws_size >= need_fast) {
        uint4* DnTf = (uint4*)d_ws;                          // 64x8x64 uint4 = 512KB
        float* q    = (float*)((char*)d_ws + 512 * 1024);    // 2048 f32
        prep_kernel<<<N_TOT / 32, 256, 0, stream>>>(disease, ak, q, DnTf);
        gat_mfma<<<B_TOT / BM, 1024, 0, stream>>>(patient, ak, q, DnTf, out);
    } else {
        float* p = (float*)d_ws;          // 8192 f32
        float* q = p + B_TOT;             // 2048 f32
        pq_fb<<<(B_TOT + N_TOT) / 4, 256, 0, stream>>>(patient, disease, ak, p, q);
        gat_fb<<<B_TOT / FBP, 256, 0, stream>>>(patient, disease, p, q, out);
    }
}